// Round 2
// baseline (1316.845 us; speedup 1.0000x reference)
//
#include <hip/hip_runtime.h>

typedef unsigned short ushort_t;
typedef _Float16 half8 __attribute__((ext_vector_type(8)));
typedef float f32x4 __attribute__((ext_vector_type(4)));

constexpr int NN  = 30000;
constexpr int EE  = 480000;
constexpr int HH  = 128;
constexpr int NEXM = 64;

#define MFMA16(a,b,c) __builtin_amdgcn_mfma_f32_16x16x32_f16((a),(b),(c),0,0,0)

__device__ __forceinline__ float fast_tanh(float x){
  float e2 = __builtin_amdgcn_exp2f(x * 2.885390081777927f);
  return 1.f - 2.f * __builtin_amdgcn_rcpf(e2 + 1.f);
}

// ---------------- weight pre-swizzle into MFMA fragment order -----------------
__global__ __launch_bounds__(256) void prep_weights(
  const float* __restrict__ fw1, const float* __restrict__ fb1,
  const float* __restrict__ fw2, const float* __restrict__ l1w,
  const float* __restrict__ l2w, const float* __restrict__ bw,
  const float* __restrict__ ow1, ushort_t* __restrict__ frags)
{
  int u = blockIdx.x*256 + threadIdx.x;
  float val;
  if (u < 24576){                       // w1T: A-frags of w1^T, K padded 50->64, row50 = bias
    int b = u >> 13; int v = u & 8191;
    int j = v & 7, lane = (v>>3)&63, fid = v>>9;     // fid = mt*2+ks
    int mt = fid>>1, ks = fid&1;
    int f1 = mt*16 + (lane&15);
    int k  = ks*32 + (lane>>4)*8 + j;
    val = (k < 50) ? fw1[(b*50 + k)*128 + f1]
        : (k == 50 ? fb1[b*128 + f1] : 0.f);
  } else {
    int v = u - 24576;
    if (v < 196608){                    // B-frags of 128x128 matrices
      int midx = v >> 14; int v2 = v & 16383;
      int g = midx/3, b = midx - g*3;
      const float* W = (g==0? fw2 : (g==1? l1w : (g==2? l2w : bw))) + b*16384;
      int j = v2&7, lane = (v2>>3)&63, fid = v2>>9;  // fid = ks*8+nt
      int ks = fid>>3, nt = fid&7;
      int k   = ks*32 + (lane>>4)*8 + j;
      int col = nt*16 + (lane&15);
      val = W[k*128 + col];
    } else {                            // out_w1 [128x64] B-frags, fid = ks*4+nt
      int v3 = v - 196608;
      int j = v3&7, lane=(v3>>3)&63, fid=v3>>9;
      int ks = fid>>2, nt = fid&3;
      int k   = ks*32 + (lane>>4)*8 + j;
      int col = nt*16 + (lane&15);
      val = ow1[k*64 + col];
    }
  }
  union { _Float16 h; ushort_t s; } cv; cv.h = (_Float16)val;
  frags[u] = cv.s;
}

// ---------------- edge geometry: d -> C, rbf (fp16, padded K=64, rbf[50]=1) ----
__global__ __launch_bounds__(256) void edge_prep(
  const float* __restrict__ pos, const int* __restrict__ ei,
  ushort_t* __restrict__ rbf, float* __restrict__ C)
{
  __shared__ float sd[64];
  int tid = threadIdx.x;
  int e0 = blockIdx.x*64;
  if (tid < 64){
    int e = e0 + tid;
    int s = ei[e], d = ei[EE + e];
    float dx = pos[s*3+0]-pos[d*3+0];
    float dy = pos[s*3+1]-pos[d*3+1];
    float dz = pos[s*3+2]-pos[d*3+2];
    float dist = sqrtf(dx*dx+dy*dy+dz*dz + 1e-12f);
    sd[tid] = dist;
    float c = 0.5f*(cosf(dist*0.31415926535897931f)+1.f);
    C[e] = (dist < 10.f) ? c : 0.f;
  }
  __syncthreads();
  int el = tid>>2, part = tid&3;
  float dist = sd[el];
  const float dd = 10.f/49.f;
  const float coefl2 = (-0.5f/(dd*dd)) * 1.4426950408889634f;
  union { ushort_t s[16]; uint4 q[2]; } ov;
  #pragma unroll
  for (int i=0;i<16;i++){
    int k = part*16 + i;
    float v;
    if (k < 50){ float t = dist - (float)k*dd; v = __builtin_amdgcn_exp2f(coefl2*t*t); }
    else v = (k==50) ? 1.f : 0.f;
    union { _Float16 h; ushort_t s; } cv; cv.h = (_Float16)v;
    ov.s[i] = cv.s;
  }
  uint4* dst = (uint4*)(rbf + (size_t)(e0+el)*64 + part*16);
  dst[0] = ov.q[0];
  dst[1] = ov.q[1];
}

// ---------------- embedding gather -------------------------------------------
__global__ __launch_bounds__(256) void embed_kernel(
  const int* __restrict__ atype, const float* __restrict__ emb, float* __restrict__ x)
{
  int id = blockIdx.x*256 + threadIdx.x;
  int a = id >> 7, f = id & 127;
  x[id] = emb[atype[a]*128 + f];
}

// ---------------- fused filter net + message + scatter ------------------------
__global__ __launch_bounds__(256,1) void filter_msg(
  const ushort_t* __restrict__ rbf, const float* __restrict__ C,
  const ushort_t* __restrict__ h, const int* __restrict__ src, const int* __restrict__ dst,
  const ushort_t* __restrict__ w1T, const ushort_t* __restrict__ w2f,
  const float* __restrict__ b2, float* __restrict__ agg)
{
  __shared__ ushort_t st[4*16*132];
  const int wave = threadIdx.x>>6, lane = threadIdx.x&63;
  const int quad = lane>>4, n15 = lane&15;
  ushort_t* tw = st + wave*16*132;

  // persistent weight fragments in VGPRs
  half8 a1[16];
  const half8* w1v = (const half8*)w1T;
  #pragma unroll
  for (int i=0;i<16;i++) a1[i] = w1v[i*64 + lane];
  half8 b2f[32];
  const half8* w2v = (const half8*)w2f;
  #pragma unroll
  for (int i=0;i<32;i++) b2f[i] = w2v[i*64 + lane];
  float bias2[8];
  #pragma unroll
  for (int nt=0;nt<8;nt++) bias2[nt] = b2[nt*16 + n15];

  const f32x4 zero4 = {0.f,0.f,0.f,0.f};
  int stride = gridDim.x*4;
  for (int tile = blockIdx.x*4 + wave; tile < EE/16; tile += stride){
    int e0 = tile*16;
    // hoist epilogue index/scalar loads so their latency overlaps MFMA work
    float Cv[4]; int sv[4], dv[4];
    #pragma unroll
    for (int r=0;r<4;r++){
      int e = e0 + quad*4 + r;
      Cv[r] = C[e]; sv[r] = src[e]; dv[r] = dst[e];
    }
    // B-frags of rbf (row = n15, k contiguous) straight from global
    const half8* rv = (const half8*)(rbf + (size_t)e0*64);
    half8 rb0 = rv[n15*8 + quad];
    half8 rb1 = rv[n15*8 + 4 + quad];
    // GEMM1: D1[f1, e] (bias folded via k=50 row)
    f32x4 acc1[8];
    #pragma unroll
    for (int mt=0;mt<8;mt++){
      acc1[mt] = MFMA16(a1[mt*2],   rb0, zero4);
      acc1[mt] = MFMA16(a1[mt*2+1], rb1, acc1[mt]);
    }
    // tanh + fp16 pack + LDS store: t[e=n15][f1 = mt*16+quad*4+r]
    #pragma unroll
    for (int mt=0;mt<8;mt++){
      union { ushort_t s[4]; uint2 v; } pk;
      #pragma unroll
      for (int r=0;r<4;r++){
        union { _Float16 h16; ushort_t s; } cv;
        cv.h16 = (_Float16)fast_tanh(acc1[mt][r]);
        pk.s[r] = cv.s;
      }
      *(uint2*)(tw + n15*132 + mt*16 + quad*4) = pk.v;
    }
    asm volatile("s_waitcnt lgkmcnt(0)" ::: "memory");
    // GEMM2: A = t from LDS (m=e), B = w2 frags (n=f2)
    f32x4 acc2[8];
    #pragma unroll
    for (int nt=0;nt<8;nt++) acc2[nt] = zero4;
    #pragma unroll
    for (int ks=0;ks<4;ks++){
      const ushort_t* ra = tw + n15*132 + ks*32 + quad*8;
      union { uint2 v[2]; half8 h16; } cc;
      cc.v[0] = *(const uint2*)(ra);
      cc.v[1] = *(const uint2*)(ra + 4);
      half8 a2 = cc.h16;
      #pragma unroll
      for (int nt=0;nt<8;nt++) acc2[nt] = MFMA16(a2, b2f[ks*8+nt], acc2[nt]);
    }
    // epilogue: W = (acc2 + b2)*C[e]; msg = h[src]*W; atomic scatter to agg[dst]
    #pragma unroll
    for (int nt=0;nt<8;nt++){
      #pragma unroll
      for (int r=0;r<4;r++){
        float Wv = (acc2[nt][r] + bias2[nt]) * Cv[r];
        float hv = (float)(*(const _Float16*)(h + (size_t)sv[r]*128 + nt*16 + n15));
        __hip_atomic_fetch_add(agg + (size_t)dv[r]*128 + nt*16 + n15, hv*Wv,
                               __ATOMIC_RELAXED, __HIP_MEMORY_SCOPE_AGENT);
      }
    }
  }
}

// ---------------- node GEMM: out_f16[N, NT*16] = [tanh](in_f32 @ W + bias) ----
template<int NT>
__global__ __launch_bounds__(256,1) void node_gemm(
  const float* __restrict__ in, const ushort_t* __restrict__ bfrag,
  const float* __restrict__ bias, int do_tanh, ushort_t* __restrict__ out)
{
  const int wave = threadIdx.x>>6, lane = threadIdx.x&63;
  const int quad = lane>>4, n15 = lane&15;
  half8 bf[NT*4];
  const half8* bv = (const half8*)bfrag;
  #pragma unroll
  for (int i=0;i<NT*4;i++) bf[i] = bv[i*64 + lane];
  float brg[NT];
  #pragma unroll
  for (int nt=0;nt<NT;nt++) brg[nt] = bias ? bias[nt*16 + n15] : 0.f;

  const f32x4 zero4 = {0.f,0.f,0.f,0.f};
  int stride = gridDim.x*4;
  for (int tile = blockIdx.x*4 + wave; tile < NN/16; tile += stride){
    int a0 = tile*16;
    const f32x4* inv = (const f32x4*)(in + (size_t)(a0 + n15)*128);
    half8 af[4];
    #pragma unroll
    for (int ks=0;ks<4;ks++){
      f32x4 lo = inv[ks*8 + quad*2];
      f32x4 hi = inv[ks*8 + quad*2 + 1];
      half8 ah;
      #pragma unroll
      for (int i=0;i<4;i++){ ah[i] = (_Float16)lo[i]; ah[4+i] = (_Float16)hi[i]; }
      af[ks] = ah;
    }
    f32x4 acc[NT];
    #pragma unroll
    for (int nt=0;nt<NT;nt++) acc[nt] = zero4;
    #pragma unroll
    for (int ks=0;ks<4;ks++){
      #pragma unroll
      for (int nt=0;nt<NT;nt++) acc[nt] = MFMA16(af[ks], bf[ks*NT+nt], acc[nt]);
    }
    #pragma unroll
    for (int nt=0;nt<NT;nt++){
      #pragma unroll
      for (int r=0;r<4;r++){
        float v = acc[nt][r] + brg[nt];
        if (do_tanh) v = fast_tanh(v);
        union { _Float16 h16; ushort_t s; } cv; cv.h16 = (_Float16)v;
        out[(size_t)(a0 + quad*4 + r)*(NT*16) + nt*16 + n15] = cv.s;
      }
    }
  }
}

// ---------------- node residual: x_f32 += t1_f16 @ W + bias -------------------
__global__ __launch_bounds__(256,1) void node_res(
  const ushort_t* __restrict__ t1, const ushort_t* __restrict__ bfrag,
  const float* __restrict__ bias, float* __restrict__ x)
{
  const int wave = threadIdx.x>>6, lane = threadIdx.x&63;
  const int quad = lane>>4, n15 = lane&15;
  half8 bf[32];
  const half8* bv = (const half8*)bfrag;
  #pragma unroll
  for (int i=0;i<32;i++) bf[i] = bv[i*64 + lane];
  float brg[8];
  #pragma unroll
  for (int nt=0;nt<8;nt++) brg[nt] = bias[nt*16 + n15];

  const f32x4 zero4 = {0.f,0.f,0.f,0.f};
  int stride = gridDim.x*4;
  for (int tile = blockIdx.x*4 + wave; tile < NN/16; tile += stride){
    int a0 = tile*16;
    const half8* inv = (const half8*)(t1 + (size_t)(a0 + n15)*128);
    half8 af[4];
    #pragma unroll
    for (int ks=0;ks<4;ks++) af[ks] = inv[ks*4 + quad];
    f32x4 acc[8];
    #pragma unroll
    for (int nt=0;nt<8;nt++) acc[nt] = zero4;
    #pragma unroll
    for (int ks=0;ks<4;ks++){
      #pragma unroll
      for (int nt=0;nt<8;nt++) acc[nt] = MFMA16(af[ks], bf[ks*8+nt], acc[nt]);
    }
    #pragma unroll
    for (int nt=0;nt<8;nt++){
      #pragma unroll
      for (int r=0;r<4;r++){
        size_t idx = (size_t)(a0 + quad*4 + r)*128 + nt*16 + n15;
        x[idx] = x[idx] + acc[nt][r] + brg[nt];
      }
    }
  }
}

// ---------------- output head stage 2 + per-molecule reduce -------------------
__global__ __launch_bounds__(256) void out_final(
  const ushort_t* __restrict__ tout, const float* __restrict__ ow2,
  const float* __restrict__ ob2, const int* __restrict__ batch, float* __restrict__ out)
{
  __shared__ float part[NEXM];
  int tid = threadIdx.x;
  if (tid < NEXM) part[tid] = 0.f;
  __syncthreads();
  int a = blockIdx.x*256 + tid;
  if (a < NN){
    float e = 0.f;
    const half8* tv = (const half8*)(tout + (size_t)a*64);
    #pragma unroll
    for (int c=0;c<8;c++){
      half8 v = tv[c];
      #pragma unroll
      for (int i=0;i<8;i++) e += (float)v[i] * ow2[c*8+i];
    }
    e += ob2[0];
    __hip_atomic_fetch_add(&part[batch[a]], e, __ATOMIC_RELAXED, __HIP_MEMORY_SCOPE_WORKGROUP);
  }
  __syncthreads();
  if (tid < NEXM)
    __hip_atomic_fetch_add(out + tid, part[tid], __ATOMIC_RELAXED, __HIP_MEMORY_SCOPE_AGENT);
}

// ---------------- host orchestration ------------------------------------------
extern "C" void kernel_launch(void* const* d_in, const int* in_sizes, int n_in,
                              void* d_out, int out_size, void* d_ws, size_t ws_size,
                              hipStream_t stream)
{
  const float* pos  = (const float*)d_in[0];
  const int*   atyp = (const int*)  d_in[1];
  const int*   ei   = (const int*)  d_in[2];
  const int*   bat  = (const int*)  d_in[3];
  const float* emb  = (const float*)d_in[4];
  const float* fw1  = (const float*)d_in[5];
  const float* fb1  = (const float*)d_in[6];
  const float* fw2  = (const float*)d_in[7];
  const float* fb2  = (const float*)d_in[8];
  const float* l1w  = (const float*)d_in[9];
  const float* l2w  = (const float*)d_in[10];
  const float* l2b  = (const float*)d_in[11];
  const float* bw   = (const float*)d_in[12];
  const float* bb   = (const float*)d_in[13];
  const float* ow1  = (const float*)d_in[14];
  const float* ob1  = (const float*)d_in[15];
  const float* ow2  = (const float*)d_in[16];
  const float* ob2  = (const float*)d_in[17];
  float* out = (float*)d_out;

  char* p = (char*)d_ws;
  ushort_t* rbf = (ushort_t*)p; p += (size_t)EE*64*2;   // 61.44 MB
  float*    C   = (float*)p;    p += (size_t)EE*4;      // 1.92 MB
  ushort_t* h   = (ushort_t*)p; p += (size_t)NN*128*2;  // 7.68 MB
  float*    x   = (float*)p;    p += (size_t)NN*128*4;  // 15.36 MB
  float*    agg = (float*)p;    p += (size_t)NN*128*4;  // 15.36 MB
  ushort_t* t1  = (ushort_t*)p; p += (size_t)NN*128*2;  // 7.68 MB (reused as t_out)
  ushort_t* frags = (ushort_t*)p;                       // 458752 B

  ushort_t* w1T = frags;
  ushort_t* w2f = frags + 24576;
  ushort_t* l1f = frags + 73728;
  ushort_t* l2f = frags + 122880;
  ushort_t* bkf = frags + 172032;
  ushort_t* o1f = frags + 221184;

  hipMemsetAsync(d_out, 0, NEXM*sizeof(float), stream);
  prep_weights<<<896,256,0,stream>>>(fw1,fb1,fw2,l1w,l2w,bw,ow1,frags);
  edge_prep<<<EE/64,256,0,stream>>>(pos, ei, rbf, C);
  embed_kernel<<<(NN*128)/256,256,0,stream>>>(atyp, emb, x);
  node_gemm<8><<<512,256,0,stream>>>(x, l1f, nullptr, 0, h);   // h = x @ lin1[0]

  for (int b=0;b<3;b++){
    hipMemsetAsync(agg, 0, (size_t)NN*128*4, stream);
    filter_msg<<<1536,256,0,stream>>>(rbf, C, h, ei, ei+EE,
                                      w1T + b*8192, w2f + b*16384, fb2 + b*128, agg);
    node_gemm<8><<<512,256,0,stream>>>(agg, l2f + b*16384, l2b + b*128, 1, t1); // t1 = tanh(agg@lin2+b)
    node_res<<<512,256,0,stream>>>(t1, bkf + b*16384, bb + b*128, x);           // x += t1@blk + bb
    if (b < 2)
      node_gemm<8><<<512,256,0,stream>>>(x, l1f + (b+1)*16384, nullptr, 0, h);  // h = x @ lin1[b+1]
  }
  node_gemm<4><<<512,256,0,stream>>>(x, o1f, ob1, 1, t1);       // t_out = tanh(x@ow1+b1)
  out_final<<<(NN+255)/256,256,0,stream>>>(t1, ow2, ob2, bat, out);
}

// Round 3
// 826.608 us; speedup vs baseline: 1.5931x; 1.5931x over previous
//
#include <hip/hip_runtime.h>

typedef unsigned short ushort_t;
typedef _Float16 half8 __attribute__((ext_vector_type(8)));
typedef float f32x4 __attribute__((ext_vector_type(4)));

constexpr int NN  = 30000;
constexpr int EE  = 480000;
constexpr int HH  = 128;
constexpr int NEXM = 64;

#define MFMA16(a,b,c) __builtin_amdgcn_mfma_f32_16x16x32_f16((a),(b),(c),0,0,0)

__device__ __forceinline__ float fast_tanh(float x){
  float e2 = __builtin_amdgcn_exp2f(x * 2.885390081777927f);
  return 1.f - 2.f * __builtin_amdgcn_rcpf(e2 + 1.f);
}

// ---------------- weight pre-swizzle into MFMA fragment order -----------------
__global__ __launch_bounds__(256) void prep_weights(
  const float* __restrict__ fw1, const float* __restrict__ fb1,
  const float* __restrict__ fw2, const float* __restrict__ l1w,
  const float* __restrict__ l2w, const float* __restrict__ bw,
  const float* __restrict__ ow1, ushort_t* __restrict__ frags)
{
  int u = blockIdx.x*256 + threadIdx.x;
  float val;
  if (u < 24576){                       // w1T: A-frags of w1^T, K padded 50->64, row50 = bias
    int b = u >> 13; int v = u & 8191;
    int j = v & 7, lane = (v>>3)&63, fid = v>>9;     // fid = mt*2+ks
    int mt = fid>>1, ks = fid&1;
    int f1 = mt*16 + (lane&15);
    int k  = ks*32 + (lane>>4)*8 + j;
    val = (k < 50) ? fw1[(b*50 + k)*128 + f1]
        : (k == 50 ? fb1[b*128 + f1] : 0.f);
  } else {
    int v = u - 24576;
    if (v < 196608){                    // B-frags of 128x128 matrices
      int midx = v >> 14; int v2 = v & 16383;
      int g = midx/3, b = midx - g*3;
      const float* W = (g==0? fw2 : (g==1? l1w : (g==2? l2w : bw))) + b*16384;
      int j = v2&7, lane = (v2>>3)&63, fid = v2>>9;  // fid = ks*8+nt
      int ks = fid>>3, nt = fid&7;
      int k   = ks*32 + (lane>>4)*8 + j;
      int col = nt*16 + (lane&15);
      val = W[k*128 + col];
    } else {                            // out_w1 [128x64] B-frags, fid = ks*4+nt
      int v3 = v - 196608;
      int j = v3&7, lane=(v3>>3)&63, fid=v3>>9;
      int ks = fid>>2, nt = fid&3;
      int k   = ks*32 + (lane>>4)*8 + j;
      int col = nt*16 + (lane&15);
      val = ow1[k*64 + col];
    }
  }
  union { _Float16 h; ushort_t s; } cv; cv.h = (_Float16)val;
  frags[u] = cv.s;
}

// ---------------- dst-sort: histogram -> scan -> scatter ----------------------
__global__ __launch_bounds__(256) void count_k(
  const int* __restrict__ ei, int* __restrict__ cnt)
{
  int e = blockIdx.x*256 + threadIdx.x;
  atomicAdd(cnt + ei[EE + e], 1);
}

__global__ __launch_bounds__(1024) void scan_k(
  const int* __restrict__ cnt, int* __restrict__ off)
{
  __shared__ int wsum[16];
  __shared__ int carry;
  int tid = threadIdx.x, lane = tid&63, w = tid>>6;
  if (tid==0) carry = 0;
  __syncthreads();
  for (int base=0; base<NN; base+=1024){
    int i = base + tid;
    int v = (i<NN) ? cnt[i] : 0;
    int s = v;
    #pragma unroll
    for (int o=1;o<64;o<<=1){ int t = __shfl_up(s,o,64); if (lane>=o) s += t; }
    if (lane==63) wsum[w] = s;
    __syncthreads();
    if (tid < 16){
      int t = wsum[tid];
      #pragma unroll
      for (int o=1;o<16;o<<=1){ int u2 = __shfl_up(t,o,16); if (tid>=o) t += u2; }
      wsum[tid] = t;
    }
    __syncthreads();
    int wbase = (w==0) ? 0 : wsum[w-1];
    if (i<NN) off[i] = carry + wbase + s - v;
    __syncthreads();
    if (tid==0) carry += wsum[15];
    __syncthreads();
  }
}

__global__ __launch_bounds__(256) void scatter_k(
  const int* __restrict__ ei, int* __restrict__ off, int* __restrict__ perm)
{
  int e = blockIdx.x*256 + threadIdx.x;
  int p = atomicAdd(off + ei[EE + e], 1);
  perm[p] = e;
}

// ---------------- edge geometry (dst-sorted order), meta packed in K-pad ------
// row layout (64 ushorts): [0..49] rbf fp16, [50]=1.0 (bias row), [51..55]=0,
// [56]=C fp16, [57]=src&0x3FFF, [58]=src>>14, [59]=dst&0x3FFF, [60]=dst>>14,
// [61..63]=0.  All pad ushorts < 0x7C00 (finite as fp16); w1T rows 51..63 are
// zero so MFMA sees finite*0 = 0.
__global__ __launch_bounds__(256) void edge_prep(
  const float* __restrict__ pos, const int* __restrict__ ei,
  const int* __restrict__ perm, ushort_t* __restrict__ rbf)
{
  __shared__ float sd[64]; __shared__ float scv[64];
  __shared__ int ssv[64]; __shared__ int sdv[64];
  int tid = threadIdx.x;
  int e0 = blockIdx.x*64;
  if (tid < 64){
    int eo = perm[e0 + tid];
    int s = ei[eo], d = ei[EE + eo];
    float dx = pos[s*3+0]-pos[d*3+0];
    float dy = pos[s*3+1]-pos[d*3+1];
    float dz = pos[s*3+2]-pos[d*3+2];
    float dist = sqrtf(dx*dx+dy*dy+dz*dz + 1e-12f);
    sd[tid] = dist; ssv[tid] = s; sdv[tid] = d;
    float c = 0.5f*(cosf(dist*0.31415926535897931f)+1.f);
    scv[tid] = (dist < 10.f) ? c : 0.f;
  }
  __syncthreads();
  int el = tid>>2, part = tid&3;
  float dist = sd[el];
  const float dd = 10.f/49.f;
  const float coefl2 = (-0.5f/(dd*dd)) * 1.4426950408889634f;
  union { ushort_t s[16]; uint4 q[2]; } ov;
  #pragma unroll
  for (int i=0;i<16;i++){
    int k = part*16 + i;
    ushort_t outv;
    if (k < 50){
      float t = dist - (float)k*dd;
      union { _Float16 h; ushort_t s; } cv; cv.h = (_Float16)__builtin_amdgcn_exp2f(coefl2*t*t);
      outv = cv.s;
    } else if (k == 50){
      outv = 0x3C00;                       // fp16 1.0 (bias row)
    } else if (k == 56){
      union { _Float16 h; ushort_t s; } cv; cv.h = (_Float16)scv[el];
      outv = cv.s;
    } else if (k == 57){ outv = (ushort_t)(ssv[el] & 0x3FFF);
    } else if (k == 58){ outv = (ushort_t)(ssv[el] >> 14);
    } else if (k == 59){ outv = (ushort_t)(sdv[el] & 0x3FFF);
    } else if (k == 60){ outv = (ushort_t)(sdv[el] >> 14);
    } else outv = 0;
    ov.s[i] = outv;
  }
  uint4* dst = (uint4*)(rbf + (size_t)(e0+el)*64 + part*16);
  dst[0] = ov.q[0];
  dst[1] = ov.q[1];
}

// ---------------- embedding gather -------------------------------------------
__global__ __launch_bounds__(256) void embed_kernel(
  const int* __restrict__ atype, const float* __restrict__ emb, float* __restrict__ x)
{
  int id = blockIdx.x*256 + threadIdx.x;
  int a = id >> 7, f = id & 127;
  x[id] = emb[atype[a]*128 + f];
}

// ---------------- fused filter net + message + merged scatter -----------------
// w2 frags live in LDS (block-shared) to cut 128 VGPRs -> 2 waves/SIMD.
// dst-sorted edges: per-lane run-merge before atomics (~3-4x fewer atomics).
__global__ __launch_bounds__(256,2) void filter_msg(
  const ushort_t* __restrict__ rbf, const ushort_t* __restrict__ h,
  const ushort_t* __restrict__ w1g, const ushort_t* __restrict__ w2g,
  const float* __restrict__ b2, float* __restrict__ agg)
{
  __shared__ ushort_t ldsW2[16384];     // 32 KB: w2 B-frags
  __shared__ ushort_t st[4*16*132];     // 16.5 KB: per-wave transpose buffer
  const int wave = threadIdx.x>>6, lane = threadIdx.x&63;
  const int quad = lane>>4, n15 = lane&15;

  // stage w2 frags to LDS (once per persistent block)
  {
    const uint4* s2 = (const uint4*)w2g; uint4* d2 = (uint4*)ldsW2;
    #pragma unroll
    for (int i=0;i<8;i++) d2[threadIdx.x + i*256] = s2[threadIdx.x + i*256];
  }
  // w1T A-frags stay in VGPRs (64 regs)
  half8 a1[16];
  const half8* w1v = (const half8*)w1g;
  #pragma unroll
  for (int i=0;i<16;i++) a1[i] = w1v[i*64 + lane];
  float bias2[8];
  #pragma unroll
  for (int nt=0;nt<8;nt++) bias2[nt] = b2[nt*16 + n15];
  __syncthreads();

  const half8* w2l = (const half8*)ldsW2;
  ushort_t* tw = st + wave*16*132;
  const f32x4 zero4 = {0.f,0.f,0.f,0.f};
  int stride = gridDim.x*4;
  for (int tile = blockIdx.x*4 + wave; tile < EE/16; tile += stride){
    int e0 = tile*16;
    const ushort_t* rowm = rbf + (size_t)e0*64;
    // decode per-edge metadata from K-pad (lines already hot from rbf reads)
    float Cv[4]; int sv[4], dv[4];
    #pragma unroll
    for (int r=0;r<4;r++){
      union { ushort_t u[8]; uint4 q; } m;
      m.q = *(const uint4*)(rowm + (quad*4+r)*64 + 56);
      union { ushort_t s; _Float16 hh; } ch; ch.s = m.u[0];
      Cv[r] = (float)ch.hh;
      sv[r] = (int)m.u[1] | ((int)m.u[2] << 14);
      dv[r] = (int)m.u[3] | ((int)m.u[4] << 14);
    }
    // B-frags of rbf
    const half8* rv = (const half8*)rowm;
    half8 rb0 = rv[n15*8 + quad];
    half8 rb1 = rv[n15*8 + 4 + quad];
    // GEMM1: D1[f1,e] (bias folded via k=50 row)
    f32x4 acc1[8];
    #pragma unroll
    for (int mt=0;mt<8;mt++){
      acc1[mt] = MFMA16(a1[mt*2],   rb0, zero4);
      acc1[mt] = MFMA16(a1[mt*2+1], rb1, acc1[mt]);
    }
    // tanh + fp16 pack + LDS transpose store
    #pragma unroll
    for (int mt=0;mt<8;mt++){
      union { ushort_t s[4]; uint2 v; } pk;
      #pragma unroll
      for (int r=0;r<4;r++){
        union { _Float16 h16; ushort_t s; } cv;
        cv.h16 = (_Float16)fast_tanh(acc1[mt][r]);
        pk.s[r] = cv.s;
      }
      *(uint2*)(tw + n15*132 + mt*16 + quad*4) = pk.v;
    }
    asm volatile("s_waitcnt lgkmcnt(0)" ::: "memory");
    // GEMM2: A = t from LDS (m=e), B = w2 frags from LDS
    f32x4 acc2[8];
    #pragma unroll
    for (int nt=0;nt<8;nt++) acc2[nt] = zero4;
    #pragma unroll
    for (int ks=0;ks<4;ks++){
      const ushort_t* ra = tw + n15*132 + ks*32 + quad*8;
      union { uint2 v[2]; half8 h16; } cc;
      cc.v[0] = *(const uint2*)(ra);
      cc.v[1] = *(const uint2*)(ra + 4);
      half8 a2 = cc.h16;
      #pragma unroll
      for (int nt=0;nt<8;nt++) acc2[nt] = MFMA16(a2, w2l[(ks*8+nt)*64 + lane], acc2[nt]);
    }
    // preload all h-gathers (latency batched)
    float hv[8][4];
    #pragma unroll
    for (int r=0;r<4;r++){
      const ushort_t* hb = h + (size_t)sv[r]*128 + n15;
      #pragma unroll
      for (int nt=0;nt<8;nt++)
        hv[nt][r] = (float)*(const _Float16*)(hb + nt*16);
    }
    // run-merged atomic scatter (dst-sorted => few runs per lane)
    #pragma unroll
    for (int nt=0;nt<8;nt++){
      float* ab = agg + nt*16 + n15;
      int cur = dv[0];
      float a = (acc2[nt][0] + bias2[nt]) * Cv[0] * hv[nt][0];
      #pragma unroll
      for (int r=1;r<4;r++){
        float m = (acc2[nt][r] + bias2[nt]) * Cv[r] * hv[nt][r];
        if (dv[r] == cur) a += m;
        else {
          __hip_atomic_fetch_add(ab + (size_t)cur*128, a, __ATOMIC_RELAXED, __HIP_MEMORY_SCOPE_AGENT);
          cur = dv[r]; a = m;
        }
      }
      __hip_atomic_fetch_add(ab + (size_t)cur*128, a, __ATOMIC_RELAXED, __HIP_MEMORY_SCOPE_AGENT);
    }
  }
}

// ---------------- node GEMM: out_f16[N, NT*16] = [tanh](in_f32 @ W + bias) ----
template<int NT>
__global__ __launch_bounds__(256,2) void node_gemm(
  const float* __restrict__ in, const ushort_t* __restrict__ bfrag,
  const float* __restrict__ bias, int do_tanh, ushort_t* __restrict__ out)
{
  const int wave = threadIdx.x>>6, lane = threadIdx.x&63;
  const int quad = lane>>4, n15 = lane&15;
  half8 bf[NT*4];
  const half8* bv = (const half8*)bfrag;
  #pragma unroll
  for (int i=0;i<NT*4;i++) bf[i] = bv[i*64 + lane];
  float brg[NT];
  #pragma unroll
  for (int nt=0;nt<NT;nt++) brg[nt] = bias ? bias[nt*16 + n15] : 0.f;

  const f32x4 zero4 = {0.f,0.f,0.f,0.f};
  int stride = gridDim.x*4;
  for (int tile = blockIdx.x*4 + wave; tile < NN/16; tile += stride){
    int a0 = tile*16;
    const f32x4* inv = (const f32x4*)(in + (size_t)(a0 + n15)*128);
    half8 af[4];
    #pragma unroll
    for (int ks=0;ks<4;ks++){
      f32x4 lo = inv[ks*8 + quad*2];
      f32x4 hi = inv[ks*8 + quad*2 + 1];
      half8 ah;
      #pragma unroll
      for (int i=0;i<4;i++){ ah[i] = (_Float16)lo[i]; ah[4+i] = (_Float16)hi[i]; }
      af[ks] = ah;
    }
    f32x4 acc[NT];
    #pragma unroll
    for (int nt=0;nt<NT;nt++) acc[nt] = zero4;
    #pragma unroll
    for (int ks=0;ks<4;ks++){
      #pragma unroll
      for (int nt=0;nt<NT;nt++) acc[nt] = MFMA16(af[ks], bf[ks*NT+nt], acc[nt]);
    }
    #pragma unroll
    for (int nt=0;nt<NT;nt++){
      #pragma unroll
      for (int r=0;r<4;r++){
        float v = acc[nt][r] + brg[nt];
        if (do_tanh) v = fast_tanh(v);
        union { _Float16 h16; ushort_t s; } cv; cv.h16 = (_Float16)v;
        out[(size_t)(a0 + quad*4 + r)*(NT*16) + nt*16 + n15] = cv.s;
      }
    }
  }
}

// ---------------- node residual: x_f32 += t1_f16 @ W + bias -------------------
__global__ __launch_bounds__(256,2) void node_res(
  const ushort_t* __restrict__ t1, const ushort_t* __restrict__ bfrag,
  const float* __restrict__ bias, float* __restrict__ x)
{
  const int wave = threadIdx.x>>6, lane = threadIdx.x&63;
  const int quad = lane>>4, n15 = lane&15;
  half8 bf[32];
  const half8* bv = (const half8*)bfrag;
  #pragma unroll
  for (int i=0;i<32;i++) bf[i] = bv[i*64 + lane];
  float brg[8];
  #pragma unroll
  for (int nt=0;nt<8;nt++) brg[nt] = bias[nt*16 + n15];

  const f32x4 zero4 = {0.f,0.f,0.f,0.f};
  int stride = gridDim.x*4;
  for (int tile = blockIdx.x*4 + wave; tile < NN/16; tile += stride){
    int a0 = tile*16;
    const half8* inv = (const half8*)(t1 + (size_t)(a0 + n15)*128);
    half8 af[4];
    #pragma unroll
    for (int ks=0;ks<4;ks++) af[ks] = inv[ks*4 + quad];
    f32x4 acc[8];
    #pragma unroll
    for (int nt=0;nt<8;nt++) acc[nt] = zero4;
    #pragma unroll
    for (int ks=0;ks<4;ks++){
      #pragma unroll
      for (int nt=0;nt<8;nt++) acc[nt] = MFMA16(af[ks], bf[ks*8+nt], acc[nt]);
    }
    #pragma unroll
    for (int nt=0;nt<8;nt++){
      #pragma unroll
      for (int r=0;r<4;r++){
        size_t idx = (size_t)(a0 + quad*4 + r)*128 + nt*16 + n15;
        x[idx] = x[idx] + acc[nt][r] + brg[nt];
      }
    }
  }
}

// ---------------- output head stage 2 + per-molecule reduce -------------------
__global__ __launch_bounds__(256) void out_final(
  const ushort_t* __restrict__ tout, const float* __restrict__ ow2,
  const float* __restrict__ ob2, const int* __restrict__ batch, float* __restrict__ out)
{
  __shared__ float part[NEXM];
  int tid = threadIdx.x;
  if (tid < NEXM) part[tid] = 0.f;
  __syncthreads();
  int a = blockIdx.x*256 + tid;
  if (a < NN){
    float e = 0.f;
    const half8* tv = (const half8*)(tout + (size_t)a*64);
    #pragma unroll
    for (int c=0;c<8;c++){
      half8 v = tv[c];
      #pragma unroll
      for (int i=0;i<8;i++) e += (float)v[i] * ow2[c*8+i];
    }
    e += ob2[0];
    __hip_atomic_fetch_add(&part[batch[a]], e, __ATOMIC_RELAXED, __HIP_MEMORY_SCOPE_WORKGROUP);
  }
  __syncthreads();
  if (tid < NEXM)
    __hip_atomic_fetch_add(out + tid, part[tid], __ATOMIC_RELAXED, __HIP_MEMORY_SCOPE_AGENT);
}

// ---------------- host orchestration ------------------------------------------
extern "C" void kernel_launch(void* const* d_in, const int* in_sizes, int n_in,
                              void* d_out, int out_size, void* d_ws, size_t ws_size,
                              hipStream_t stream)
{
  const float* pos  = (const float*)d_in[0];
  const int*   atyp = (const int*)  d_in[1];
  const int*   ei   = (const int*)  d_in[2];
  const int*   bat  = (const int*)  d_in[3];
  const float* emb  = (const float*)d_in[4];
  const float* fw1  = (const float*)d_in[5];
  const float* fb1  = (const float*)d_in[6];
  const float* fw2  = (const float*)d_in[7];
  const float* fb2  = (const float*)d_in[8];
  const float* l1w  = (const float*)d_in[9];
  const float* l2w  = (const float*)d_in[10];
  const float* l2b  = (const float*)d_in[11];
  const float* bw   = (const float*)d_in[12];
  const float* bb   = (const float*)d_in[13];
  const float* ow1  = (const float*)d_in[14];
  const float* ob1  = (const float*)d_in[15];
  const float* ow2  = (const float*)d_in[16];
  const float* ob2  = (const float*)d_in[17];
  float* out = (float*)d_out;

  char* p = (char*)d_ws;
  ushort_t* rbf = (ushort_t*)p; p += (size_t)EE*64*2;   // 61.44 MB (incl packed meta)
  ushort_t* h   = (ushort_t*)p; p += (size_t)NN*128*2;  //  7.68 MB
  float*    x   = (float*)p;    p += (size_t)NN*128*4;  // 15.36 MB
  float*    agg = (float*)p;    p += (size_t)NN*128*4;  // 15.36 MB
  ushort_t* t1  = (ushort_t*)p; p += (size_t)NN*128*2;  //  7.68 MB (reused as t_out)
  ushort_t* frags = (ushort_t*)p;                       // 458752 B   => total ~108 MB

  // aliased scratch (lifetimes do not overlap their hosts):
  int* cnt  = (int*)agg;                      // [NN] used only before first agg memset
  int* off  = (int*)((char*)agg + 131072);    // [NN]
  int* perm = (int*)t1;                       // [EE] dead after edge_prep; t1 written later

  ushort_t* w1T = frags;
  ushort_t* w2f = frags + 24576;
  ushort_t* l1f = frags + 73728;
  ushort_t* l2f = frags + 122880;
  ushort_t* bkf = frags + 172032;
  ushort_t* o1f = frags + 221184;

  hipMemsetAsync(d_out, 0, NEXM*sizeof(float), stream);
  hipMemsetAsync(cnt, 0, NN*sizeof(int), stream);
  prep_weights<<<896,256,0,stream>>>(fw1,fb1,fw2,l1w,l2w,bw,ow1,frags);
  count_k<<<EE/256,256,0,stream>>>(ei, cnt);
  scan_k<<<1,1024,0,stream>>>(cnt, off);
  scatter_k<<<EE/256,256,0,stream>>>(ei, off, perm);
  edge_prep<<<EE/64,256,0,stream>>>(pos, ei, perm, rbf);
  embed_kernel<<<(NN*128)/256,256,0,stream>>>(atyp, emb, x);
  node_gemm<8><<<512,256,0,stream>>>(x, l1f, nullptr, 0, h);   // h = x @ lin1[0]

  for (int b=0;b<3;b++){
    hipMemsetAsync(agg, 0, (size_t)NN*128*4, stream);
    filter_msg<<<512,256,0,stream>>>(rbf, h,
                                     w1T + b*8192, w2f + b*16384, fb2 + b*128, agg);
    node_gemm<8><<<512,256,0,stream>>>(agg, l2f + b*16384, l2b + b*128, 1, t1); // t1 = tanh(agg@lin2+b)
    node_res<<<512,256,0,stream>>>(t1, bkf + b*16384, bb + b*128, x);           // x += t1@blk + bb
    if (b < 2)
      node_gemm<8><<<512,256,0,stream>>>(x, l1f + (b+1)*16384, nullptr, 0, h);  // h = x @ lin1[b+1]
  }
  node_gemm<4><<<512,256,0,stream>>>(x, o1f, ob1, 1, t1);       // t_out = tanh(x@ow1+b1)
  out_final<<<(NN+255)/256,256,0,stream>>>(t1, ow2, ob2, bat, out);
}